// Round 1
// baseline (476.497 us; speedup 1.0000x reference)
//
#include <hip/hip_runtime.h>
#include <stdint.h>

#define HH 2048
#define WW 2048
#define NS 1024
#define NIMG 64
#define ESZ 256
#define NCOL 69   // x, y, h, w, d, c[64]

// ---------------------------------------------------------------------------
// Kernel 1: decode samples, compute stable depth rank, scatter packed sprite
// records (x1:11 | y1:11 | imgidx:6) into ws in depth-sorted order.
// ---------------------------------------------------------------------------
__global__ __launch_bounds__(1024) void prep_kernel(const float* __restrict__ data,
                                                    uint32_t* __restrict__ pos) {
    __shared__ float ds[NS];
    const int t = threadIdx.x;
    const float* row = data + t * NCOL;

    const float d = row[4];
    const int x = (int)rintf(row[0] * (float)HH);   // rintf = round half to even, matches jnp.round
    const int y = (int)rintf(row[1] * (float)WW);
    const int h = (int)rintf(row[2] * (float)HH);
    const int w = (int)rintf(row[3] * (float)WW);
    const int x1 = x - h / 2;                       // h,w positive -> C division == floor
    const int y1 = y - w / 2;

    // argmax over the 64 coefficients (first occurrence of max, like jnp.argmax)
    float best = row[5];
    int bi = 0;
    #pragma unroll 4
    for (int j = 1; j < NIMG; ++j) {
        float v = row[5 + j];
        if (v > best) { best = v; bi = j; }
    }

    ds[t] = d;
    __syncthreads();

    // stable rank: #{j : d[j] < d[t]  or  (d[j] == d[t] and j < t)}
    int rank = 0;
    for (int j = 0; j < NS; ++j) {
        float dj = ds[j];
        rank += (int)((dj < d) | ((dj == d) & (j < t)));
    }

    pos[rank] = ((uint32_t)x1 << 17) | ((uint32_t)y1 << 6) | (uint32_t)bi;
}

// ---------------------------------------------------------------------------
// Kernel 2: one block per 16x16 canvas tile. Bin depth-sorted sprites against
// the tile (order-preserving ballot compaction into LDS), then per-pixel
// composite:   rgb = rgb*(1-a) + sprite_rgb*a   (alpha stays exactly 1.0).
// ---------------------------------------------------------------------------
__global__ __launch_bounds__(256) void comp_kernel(const float* __restrict__ images,
                                                   const uint32_t* __restrict__ pos,
                                                   float* __restrict__ out) {
    __shared__ uint32_t list[NS];
    __shared__ int wcnt[4];

    const int tid  = threadIdx.x;
    const int lane = tid & 63;
    const int wv   = tid >> 6;

    const int tileR = blockIdx.x >> 7;    // 2048/16 = 128 tiles per dimension
    const int tileC = blockIdx.x & 127;
    const int r0 = tileR * 16;
    const int c0 = tileC * 16;

    // ---- binning: keep sprites whose 256x256 bbox intersects this tile ----
    int run = 0;
    for (int base = 0; base < NS; base += 256) {
        const uint32_t p = pos[base + tid];
        const int x1 = (int)(p >> 17);
        const int y1 = (int)((p >> 6) & 0x7FF);
        const bool hit = (x1 >= r0 - (ESZ - 1)) && (x1 <= r0 + 15) &&
                         (y1 >= c0 - (ESZ - 1)) && (y1 <= c0 + 15);
        const uint64_t m = __ballot(hit);
        if (lane == 0) wcnt[wv] = __popcll(m);
        __syncthreads();
        int off = run;
        for (int w2 = 0; w2 < wv; ++w2) off += wcnt[w2];
        if (hit) {
            const int slot = __popcll(m & ((1ull << lane) - 1ull));
            list[off + slot] = p;
        }
        run += wcnt[0] + wcnt[1] + wcnt[2] + wcnt[3];
        __syncthreads();   // protects wcnt for next iter; publishes list writes
    }
    const int n = run;

    // ---- per-pixel composite over the tile's sprite list (depth order) ----
    const int px = c0 + (tid & 15);   // column
    const int py = r0 + (tid >> 4);   // row
    float r = 1.0f, g = 1.0f, b = 1.0f;

    for (int s = 0; s < n; ++s) {
        const uint32_t p = list[s];                 // uniform -> LDS broadcast
        const int x1 = (int)(p >> 17);
        const int y1 = (int)((p >> 6) & 0x7FF);
        const int ii = (int)(p & 0x3F);
        const int sy = py - x1;
        const int sx = px - y1;
        if ((unsigned)sy < ESZ && (unsigned)sx < ESZ) {
            const float* sp = images + (size_t)ii * (4 * ESZ * ESZ) + sy * ESZ + sx;
            const float sr = sp[0];
            const float sg = sp[ESZ * ESZ];
            const float sb = sp[2 * ESZ * ESZ];
            const float a  = sp[3 * ESZ * ESZ];
            const float ia = 1.0f - a;
            r = r * ia + sr * a;
            g = g * ia + sg * a;
            b = b * ia + sb * a;
        }
    }

    const size_t o = (size_t)py * WW + px;
    out[o]                        = r;
    out[(size_t)HH * WW     + o]  = g;
    out[(size_t)2 * HH * WW + o]  = b;
    out[(size_t)3 * HH * WW + o]  = 1.0f;   // alpha is exactly 1.0 everywhere
}

extern "C" void kernel_launch(void* const* d_in, const int* in_sizes, int n_in,
                              void* d_out, int out_size, void* d_ws, size_t ws_size,
                              hipStream_t stream) {
    const float* data   = (const float*)d_in[0];
    const float* images = (const float*)d_in[1];
    float* out          = (float*)d_out;
    uint32_t* pos       = (uint32_t*)d_ws;   // 1024 * 4 B of scratch

    prep_kernel<<<1, NS, 0, stream>>>(data, pos);
    comp_kernel<<<(HH / 16) * (WW / 16), 256, 0, stream>>>(images, pos, out);
}

// Round 2
// 209.022 us; speedup vs baseline: 2.2797x; 2.2797x over previous
//
#include <hip/hip_runtime.h>
#include <hip/hip_fp16.h>
#include <stdint.h>

#define HH 2048
#define WW 2048
#define NS 1024
#define NIMG 64
#define ESZ 256
#define NCOL 69   // x, y, h, w, d, c[64]

// ---------------------------------------------------------------------------
// Kernel 1: decode samples, compute stable depth rank, scatter packed sprite
// records (x1:11 | y1:11 | imgidx:6) into ws in depth-sorted order.
// ---------------------------------------------------------------------------
__global__ __launch_bounds__(1024) void prep_kernel(const float* __restrict__ data,
                                                    uint32_t* __restrict__ pos) {
    __shared__ float ds[NS];
    const int t = threadIdx.x;
    const float* row = data + t * NCOL;

    const float d = row[4];
    const int x = (int)rintf(row[0] * (float)HH);   // round-half-even == jnp.round
    const int y = (int)rintf(row[1] * (float)WW);
    const int h = (int)rintf(row[2] * (float)HH);
    const int w = (int)rintf(row[3] * (float)WW);
    const int x1 = x - h / 2;
    const int y1 = y - w / 2;

    float best = row[5];
    int bi = 0;
    #pragma unroll 4
    for (int j = 1; j < NIMG; ++j) {
        float v = row[5 + j];
        if (v > best) { best = v; bi = j; }
    }

    ds[t] = d;
    __syncthreads();

    int rank = 0;
    for (int j = 0; j < NS; ++j) {
        float dj = ds[j];
        rank += (int)((dj < d) | ((dj == d) & (j < t)));
    }

    pos[rank] = ((uint32_t)x1 << 17) | ((uint32_t)y1 << 6) | (uint32_t)bi;
}

// ---------------------------------------------------------------------------
// Kernel 1b: planar f32 [img][c][256][256]  ->  interleaved fp16 RGBA (uint2)
// ---------------------------------------------------------------------------
__global__ __launch_bounds__(256) void interleave_kernel(const float* __restrict__ images,
                                                         uint2* __restrict__ hbuf) {
    const size_t g = (size_t)blockIdx.x * 256 + threadIdx.x;  // [0, 64*65536)
    const size_t img = g >> 16;
    const size_t p   = g & 65535;
    const float* base = images + img * (size_t)(4 * 65536) + p;
    const float r = base[0];
    const float gg = base[65536];
    const float b = base[2 * 65536];
    const float a = base[3 * 65536];
    const __half2 rg = __floats2half2_rn(r, gg);
    const __half2 ba = __floats2half2_rn(b, a);
    uint2 v;
    v.x = *(const unsigned int*)&rg;
    v.y = *(const unsigned int*)&ba;
    hbuf[g] = v;
}

// ---------------------------------------------------------------------------
// Kernel 2 (fast path): one block per 32x32 tile, 4 px/thread (4 quadrants of
// 16x16), fp16 interleaved sprite reads (one 8B load per covered pair).
// ---------------------------------------------------------------------------
__global__ __launch_bounds__(256) void comp_half_kernel(const uint2* __restrict__ hbuf,
                                                        const uint32_t* __restrict__ pos,
                                                        float* __restrict__ out) {
    __shared__ uint32_t list[NS];
    __shared__ int wcnt[4];

    const int tid  = threadIdx.x;
    const int lane = tid & 63;
    const int wv   = tid >> 6;

    const int tileR = blockIdx.x >> 6;    // 2048/32 = 64 tiles per dim
    const int tileC = blockIdx.x & 63;
    const int r0 = tileR * 32;
    const int c0 = tileC * 32;

    // ---- binning: sprites whose 256x256 bbox intersects this 32x32 tile ----
    int run = 0;
    for (int base = 0; base < NS; base += 256) {
        const uint32_t p = pos[base + tid];
        const int x1 = (int)(p >> 17);
        const int y1 = (int)((p >> 6) & 0x7FF);
        const bool hit = (x1 >= r0 - (ESZ - 1)) && (x1 <= r0 + 31) &&
                         (y1 >= c0 - (ESZ - 1)) && (y1 <= c0 + 31);
        const uint64_t m = __ballot(hit);
        if (lane == 0) wcnt[wv] = __popcll(m);
        __syncthreads();
        int off = run;
        for (int w2 = 0; w2 < wv; ++w2) off += wcnt[w2];
        if (hit) {
            const int slot = __popcll(m & ((1ull << lane) - 1ull));
            list[off + slot] = p;
        }
        run += wcnt[0] + wcnt[1] + wcnt[2] + wcnt[3];
        __syncthreads();
    }
    const int n = run;

    // ---- per-thread: 4 pixels (quadrants), independent load streams ----
    const int px0 = c0 + (tid & 15);
    const int py0 = r0 + (tid >> 4);

    float rr[4], gg[4], bb[4];
    #pragma unroll
    for (int q = 0; q < 4; ++q) { rr[q] = 1.0f; gg[q] = 1.0f; bb[q] = 1.0f; }

    for (int s = 0; s < n; ++s) {
        const uint32_t p = list[s];                 // uniform -> LDS broadcast
        const int x1 = (int)(p >> 17);
        const int y1 = (int)((p >> 6) & 0x7FF);
        const size_t ib = ((size_t)(p & 0x3F)) << 16;
        const int ry = py0 - x1;
        const int rx = px0 - y1;
        #pragma unroll
        for (int q = 0; q < 4; ++q) {
            const int sy = ry + ((q >> 1) << 4);
            const int sx = rx + ((q & 1) << 4);
            if ((unsigned)sy < ESZ && (unsigned)sx < ESZ) {
                const uint2 v = hbuf[ib + (size_t)((sy << 8) + sx)];
                const __half2 rg = *(const __half2*)&v.x;
                const __half2 ba = *(const __half2*)&v.y;
                const float sr = __low2float(rg);
                const float sg = __high2float(rg);
                const float sb = __low2float(ba);
                const float a  = __high2float(ba);
                const float ia = 1.0f - a;
                rr[q] = rr[q] * ia + sr * a;
                gg[q] = gg[q] * ia + sg * a;
                bb[q] = bb[q] * ia + sb * a;
            }
        }
    }

    #pragma unroll
    for (int q = 0; q < 4; ++q) {
        const int py = py0 + ((q >> 1) << 4);
        const int px = px0 + ((q & 1) << 4);
        const size_t o = (size_t)py * WW + px;
        out[o]                        = rr[q];
        out[(size_t)HH * WW     + o]  = gg[q];
        out[(size_t)2 * HH * WW + o]  = bb[q];
        out[(size_t)3 * HH * WW + o]  = 1.0f;
    }
}

// ---------------------------------------------------------------------------
// Kernel 2 (fallback, fp32 planar) — used only if ws_size is too small.
// ---------------------------------------------------------------------------
__global__ __launch_bounds__(256) void comp_kernel(const float* __restrict__ images,
                                                   const uint32_t* __restrict__ pos,
                                                   float* __restrict__ out) {
    __shared__ uint32_t list[NS];
    __shared__ int wcnt[4];

    const int tid  = threadIdx.x;
    const int lane = tid & 63;
    const int wv   = tid >> 6;

    const int tileR = blockIdx.x >> 7;
    const int tileC = blockIdx.x & 127;
    const int r0 = tileR * 16;
    const int c0 = tileC * 16;

    int run = 0;
    for (int base = 0; base < NS; base += 256) {
        const uint32_t p = pos[base + tid];
        const int x1 = (int)(p >> 17);
        const int y1 = (int)((p >> 6) & 0x7FF);
        const bool hit = (x1 >= r0 - (ESZ - 1)) && (x1 <= r0 + 15) &&
                         (y1 >= c0 - (ESZ - 1)) && (y1 <= c0 + 15);
        const uint64_t m = __ballot(hit);
        if (lane == 0) wcnt[wv] = __popcll(m);
        __syncthreads();
        int off = run;
        for (int w2 = 0; w2 < wv; ++w2) off += wcnt[w2];
        if (hit) {
            const int slot = __popcll(m & ((1ull << lane) - 1ull));
            list[off + slot] = p;
        }
        run += wcnt[0] + wcnt[1] + wcnt[2] + wcnt[3];
        __syncthreads();
    }
    const int n = run;

    const int px = c0 + (tid & 15);
    const int py = r0 + (tid >> 4);
    float r = 1.0f, g = 1.0f, b = 1.0f;

    for (int s = 0; s < n; ++s) {
        const uint32_t p = list[s];
        const int x1 = (int)(p >> 17);
        const int y1 = (int)((p >> 6) & 0x7FF);
        const int ii = (int)(p & 0x3F);
        const int sy = py - x1;
        const int sx = px - y1;
        if ((unsigned)sy < ESZ && (unsigned)sx < ESZ) {
            const float* sp = images + (size_t)ii * (4 * ESZ * ESZ) + sy * ESZ + sx;
            const float sr = sp[0];
            const float sg = sp[ESZ * ESZ];
            const float sb = sp[2 * ESZ * ESZ];
            const float a  = sp[3 * ESZ * ESZ];
            const float ia = 1.0f - a;
            r = r * ia + sr * a;
            g = g * ia + sg * a;
            b = b * ia + sb * a;
        }
    }

    const size_t o = (size_t)py * WW + px;
    out[o]                        = r;
    out[(size_t)HH * WW     + o]  = g;
    out[(size_t)2 * HH * WW + o]  = b;
    out[(size_t)3 * HH * WW + o]  = 1.0f;
}

extern "C" void kernel_launch(void* const* d_in, const int* in_sizes, int n_in,
                              void* d_out, int out_size, void* d_ws, size_t ws_size,
                              hipStream_t stream) {
    const float* data   = (const float*)d_in[0];
    const float* images = (const float*)d_in[1];
    float* out          = (float*)d_out;

    uint32_t* pos = (uint32_t*)d_ws;                           // 4 KB
    const size_t hbuf_off = 4096;
    const size_t hbuf_bytes = (size_t)NIMG * 65536 * 8;        // 33.5 MB fp16 RGBA

    prep_kernel<<<1, NS, 0, stream>>>(data, pos);

    if (ws_size >= hbuf_off + hbuf_bytes) {
        uint2* hbuf = (uint2*)((char*)d_ws + hbuf_off);
        interleave_kernel<<<(NIMG * 65536) / 256, 256, 0, stream>>>(images, hbuf);
        comp_half_kernel<<<(HH / 32) * (WW / 32), 256, 0, stream>>>(hbuf, pos, out);
    } else {
        comp_kernel<<<(HH / 16) * (WW / 16), 256, 0, stream>>>(images, pos, out);
    }
}

// Round 3
// 191.221 us; speedup vs baseline: 2.4919x; 1.0931x over previous
//
#include <hip/hip_runtime.h>
#include <hip/hip_fp16.h>
#include <stdint.h>

#define HH 2048
#define WW 2048
#define NS 1024
#define NIMG 64
#define ESZ 256
#define NCOL 69      // x, y, h, w, d, c[64]
#define EPS_T 0.001f // transmittance cutoff; truncation error <= EPS_T

#define NBLK_IL (NIMG * 65536 / 256)   // 16384 interleave blocks

// ---------------------------------------------------------------------------
// Fused kernel: blocks [0,16384) interleave planar f32 -> fp16 RGBA;
// block 16384 decodes samples + computes stable depth-sorted packed records.
// ---------------------------------------------------------------------------
__global__ __launch_bounds__(256) void prep_interleave_kernel(const float* __restrict__ data,
                                                              const float* __restrict__ images,
                                                              uint2* __restrict__ hbuf,
                                                              uint32_t* __restrict__ pos) {
    const int tid = threadIdx.x;
    if (blockIdx.x < NBLK_IL) {
        // ---- interleave: [img][c][256][256] f32 -> [img][p] fp16 RGBA ----
        const size_t g = (size_t)blockIdx.x * 256 + tid;
        const size_t img = g >> 16;
        const size_t p   = g & 65535;
        const float* base = images + img * (size_t)(4 * 65536) + p;
        const float r  = base[0];
        const float gg = base[65536];
        const float b  = base[2 * 65536];
        const float a  = base[3 * 65536];
        const __half2 rg = __floats2half2_rn(r, gg);
        const __half2 ba = __floats2half2_rn(b, a);
        uint2 v;
        v.x = *(const unsigned int*)&rg;
        v.y = *(const unsigned int*)&ba;
        hbuf[g] = v;
        return;
    }

    // ---- prep: 256 threads x 4 samples ----
    __shared__ float ds[NS];
    float    dd[4];
    uint32_t pk[4];
    #pragma unroll
    for (int k = 0; k < 4; ++k) {
        const int s = tid + 256 * k;
        const float* row = data + s * NCOL;
        const float d = row[4];
        const int x = (int)rintf(row[0] * (float)HH);   // round-half-even == jnp.round
        const int y = (int)rintf(row[1] * (float)WW);
        const int h = (int)rintf(row[2] * (float)HH);
        const int w = (int)rintf(row[3] * (float)WW);
        const int x1 = x - h / 2;
        const int y1 = y - w / 2;
        float best = row[5];
        int bi = 0;
        for (int j = 1; j < NIMG; ++j) {
            float v = row[5 + j];
            if (v > best) { best = v; bi = j; }
        }
        dd[k] = d;
        pk[k] = ((uint32_t)x1 << 17) | ((uint32_t)y1 << 6) | (uint32_t)bi;
        ds[s] = d;
    }
    __syncthreads();

    int rank[4] = {0, 0, 0, 0};
    for (int j = 0; j < NS; ++j) {
        const float dj = ds[j];   // uniform -> LDS broadcast
        #pragma unroll
        for (int k = 0; k < 4; ++k) {
            const int s = tid + 256 * k;
            rank[k] += (int)((dj < dd[k]) | ((dj == dd[k]) & (j < s)));
        }
    }
    #pragma unroll
    for (int k = 0; k < 4; ++k) pos[rank[k]] = pk[k];
}

// ---------------------------------------------------------------------------
// Composite: one block per 32x32 tile, 4 px/thread. Front-to-back with
// transmittance + per-lane predicated loads + wave-level early termination.
//   out += T*a*s;  T *= (1-a);  final: out += T*1 (white canvas), alpha = 1.
// ---------------------------------------------------------------------------
__global__ __launch_bounds__(256) void comp_half_kernel(const uint2* __restrict__ hbuf,
                                                        const uint32_t* __restrict__ pos,
                                                        float* __restrict__ out) {
    __shared__ uint32_t list[NS];
    __shared__ int wcnt[4];

    const int tid  = threadIdx.x;
    const int lane = tid & 63;
    const int wv   = tid >> 6;

    const int tileR = blockIdx.x >> 6;    // 64x64 tiles of 32x32
    const int tileC = blockIdx.x & 63;
    const int r0 = tileR * 32;
    const int c0 = tileC * 32;

    // ---- binning: sprites whose bbox intersects this tile (depth order) ----
    int run = 0;
    for (int base = 0; base < NS; base += 256) {
        const uint32_t p = pos[base + tid];
        const int x1 = (int)(p >> 17);
        const int y1 = (int)((p >> 6) & 0x7FF);
        const bool hit = (x1 >= r0 - (ESZ - 1)) && (x1 <= r0 + 31) &&
                         (y1 >= c0 - (ESZ - 1)) && (y1 <= c0 + 31);
        const uint64_t m = __ballot(hit);
        if (lane == 0) wcnt[wv] = __popcll(m);
        __syncthreads();
        int off = run;
        for (int w2 = 0; w2 < wv; ++w2) off += wcnt[w2];
        if (hit) {
            const int slot = __popcll(m & ((1ull << lane) - 1ull));
            list[off + slot] = p;
        }
        run += wcnt[0] + wcnt[1] + wcnt[2] + wcnt[3];
        __syncthreads();
    }
    const int n = run;

    // ---- per-thread: 4 pixels (16x16 quadrants of the 32x32 tile) ----
    const int px0 = c0 + (tid & 15);
    const int py0 = r0 + (tid >> 4);

    float cr[4], cg[4], cb[4], T[4];
    #pragma unroll
    for (int q = 0; q < 4; ++q) { cr[q] = 0.0f; cg[q] = 0.0f; cb[q] = 0.0f; T[q] = 1.0f; }

    // front-to-back: list is sorted back-to-front, so walk it in reverse
    for (int s = n - 1; s >= 0; --s) {
        const uint32_t p = list[s];                 // uniform -> LDS broadcast
        const int x1 = (int)(p >> 17);
        const int y1 = (int)((p >> 6) & 0x7FF);
        const size_t ib = ((size_t)(p & 0x3F)) << 16;
        const int ry = py0 - x1;
        const int rx = px0 - y1;
        #pragma unroll
        for (int q = 0; q < 4; ++q) {
            if (T[q] > EPS_T) {
                const int sy = ry + ((q >> 1) << 4);
                const int sx = rx + ((q & 1) << 4);
                if ((unsigned)sy < ESZ && (unsigned)sx < ESZ) {
                    const uint2 v = hbuf[ib + (size_t)((sy << 8) + sx)];
                    const __half2 rg = *(const __half2*)&v.x;
                    const __half2 ba = *(const __half2*)&v.y;
                    const float sr = __low2float(rg);
                    const float sg = __high2float(rg);
                    const float sb = __low2float(ba);
                    const float a  = __high2float(ba);
                    const float w  = T[q] * a;
                    cr[q] += w * sr;
                    cg[q] += w * sg;
                    cb[q] += w * sb;
                    T[q] *= (1.0f - a);
                }
            }
        }
        const bool alive = (T[0] > EPS_T) | (T[1] > EPS_T) | (T[2] > EPS_T) | (T[3] > EPS_T);
        if (!__any(alive)) break;
    }

    #pragma unroll
    for (int q = 0; q < 4; ++q) {
        const int py = py0 + ((q >> 1) << 4);
        const int px = px0 + ((q & 1) << 4);
        const size_t o = (size_t)py * WW + px;
        out[o]                        = cr[q] + T[q];   // white canvas shows through
        out[(size_t)HH * WW     + o]  = cg[q] + T[q];
        out[(size_t)2 * HH * WW + o]  = cb[q] + T[q];
        out[(size_t)3 * HH * WW + o]  = 1.0f;
    }
}

// ---------------------------------------------------------------------------
// Fallback (fp32 planar, back-to-front "over") — only if ws too small.
// ---------------------------------------------------------------------------
__global__ __launch_bounds__(1024) void prep_kernel(const float* __restrict__ data,
                                                    uint32_t* __restrict__ pos) {
    __shared__ float ds[NS];
    const int t = threadIdx.x;
    const float* row = data + t * NCOL;
    const float d = row[4];
    const int x = (int)rintf(row[0] * (float)HH);
    const int y = (int)rintf(row[1] * (float)WW);
    const int h = (int)rintf(row[2] * (float)HH);
    const int w = (int)rintf(row[3] * (float)WW);
    const int x1 = x - h / 2;
    const int y1 = y - w / 2;
    float best = row[5];
    int bi = 0;
    for (int j = 1; j < NIMG; ++j) {
        float v = row[5 + j];
        if (v > best) { best = v; bi = j; }
    }
    ds[t] = d;
    __syncthreads();
    int rank = 0;
    for (int j = 0; j < NS; ++j) {
        float dj = ds[j];
        rank += (int)((dj < d) | ((dj == d) & (j < t)));
    }
    pos[rank] = ((uint32_t)x1 << 17) | ((uint32_t)y1 << 6) | (uint32_t)bi;
}

__global__ __launch_bounds__(256) void comp_kernel(const float* __restrict__ images,
                                                   const uint32_t* __restrict__ pos,
                                                   float* __restrict__ out) {
    __shared__ uint32_t list[NS];
    __shared__ int wcnt[4];
    const int tid  = threadIdx.x;
    const int lane = tid & 63;
    const int wv   = tid >> 6;
    const int tileR = blockIdx.x >> 7;
    const int tileC = blockIdx.x & 127;
    const int r0 = tileR * 16;
    const int c0 = tileC * 16;
    int run = 0;
    for (int base = 0; base < NS; base += 256) {
        const uint32_t p = pos[base + tid];
        const int x1 = (int)(p >> 17);
        const int y1 = (int)((p >> 6) & 0x7FF);
        const bool hit = (x1 >= r0 - (ESZ - 1)) && (x1 <= r0 + 15) &&
                         (y1 >= c0 - (ESZ - 1)) && (y1 <= c0 + 15);
        const uint64_t m = __ballot(hit);
        if (lane == 0) wcnt[wv] = __popcll(m);
        __syncthreads();
        int off = run;
        for (int w2 = 0; w2 < wv; ++w2) off += wcnt[w2];
        if (hit) {
            const int slot = __popcll(m & ((1ull << lane) - 1ull));
            list[off + slot] = p;
        }
        run += wcnt[0] + wcnt[1] + wcnt[2] + wcnt[3];
        __syncthreads();
    }
    const int n = run;
    const int px = c0 + (tid & 15);
    const int py = r0 + (tid >> 4);
    float r = 1.0f, g = 1.0f, b = 1.0f;
    for (int s = 0; s < n; ++s) {
        const uint32_t p = list[s];
        const int x1 = (int)(p >> 17);
        const int y1 = (int)((p >> 6) & 0x7FF);
        const int ii = (int)(p & 0x3F);
        const int sy = py - x1;
        const int sx = px - y1;
        if ((unsigned)sy < ESZ && (unsigned)sx < ESZ) {
            const float* sp = images + (size_t)ii * (4 * ESZ * ESZ) + sy * ESZ + sx;
            const float sr = sp[0];
            const float sg = sp[ESZ * ESZ];
            const float sb = sp[2 * ESZ * ESZ];
            const float a  = sp[3 * ESZ * ESZ];
            const float ia = 1.0f - a;
            r = r * ia + sr * a;
            g = g * ia + sg * a;
            b = b * ia + sb * a;
        }
    }
    const size_t o = (size_t)py * WW + px;
    out[o]                        = r;
    out[(size_t)HH * WW     + o]  = g;
    out[(size_t)2 * HH * WW + o]  = b;
    out[(size_t)3 * HH * WW + o]  = 1.0f;
}

extern "C" void kernel_launch(void* const* d_in, const int* in_sizes, int n_in,
                              void* d_out, int out_size, void* d_ws, size_t ws_size,
                              hipStream_t stream) {
    const float* data   = (const float*)d_in[0];
    const float* images = (const float*)d_in[1];
    float* out          = (float*)d_out;

    uint32_t* pos = (uint32_t*)d_ws;                           // 4 KB
    const size_t hbuf_off = 4096;
    const size_t hbuf_bytes = (size_t)NIMG * 65536 * 8;        // 33.5 MB fp16 RGBA

    if (ws_size >= hbuf_off + hbuf_bytes) {
        uint2* hbuf = (uint2*)((char*)d_ws + hbuf_off);
        prep_interleave_kernel<<<NBLK_IL + 1, 256, 0, stream>>>(data, images, hbuf, pos);
        comp_half_kernel<<<(HH / 32) * (WW / 32), 256, 0, stream>>>(hbuf, pos, out);
    } else {
        prep_kernel<<<1, NS, 0, stream>>>(data, pos);
        comp_kernel<<<(HH / 16) * (WW / 16), 256, 0, stream>>>(images, pos, out);
    }
}

// Round 4
// 135.300 us; speedup vs baseline: 3.5218x; 1.4133x over previous
//
#include <hip/hip_runtime.h>
#include <hip/hip_fp16.h>
#include <stdint.h>

#define HH 2048
#define WW 2048
#define NS 1024
#define NIMG 64
#define ESZ 256
#define NCOL 69      // x, y, h, w, d, c[64]
#define EPS_T 0.001f // transmittance cutoff; truncation error <= EPS_T

#define NBLK_PREP 4
#define PXPT 4                                        // pixels per thread (interleave)
#define NBLK_IL (NIMG * 65536 / (256 * PXPT))         // 4096 interleave blocks

// ---------------------------------------------------------------------------
// Fused kernel. Blocks [0,4): decode+rank 256 samples each (runs first, hides
// under interleave). Blocks [4, 4+4096): planar f32 -> fp16 RGBA interleave,
// 4 px/thread with float4 loads / uint4 stores.
// ---------------------------------------------------------------------------
__global__ __launch_bounds__(256) void prep_interleave_kernel(const float* __restrict__ data,
                                                              const float* __restrict__ images,
                                                              uint2* __restrict__ hbuf,
                                                              uint32_t* __restrict__ pos) {
    const int tid = threadIdx.x;

    if (blockIdx.x >= NBLK_PREP) {
        // ---- interleave ----
        const size_t g0 = ((size_t)(blockIdx.x - NBLK_PREP) * 256 + tid) * PXPT;
        const size_t img = g0 >> 16;
        const size_t p0  = g0 & 65535;
        const float* base = images + img * (size_t)(4 * 65536) + p0;
        const float4 r4 = *(const float4*)(base);
        const float4 g4 = *(const float4*)(base + 65536);
        const float4 b4 = *(const float4*)(base + 2 * 65536);
        const float4 a4 = *(const float4*)(base + 3 * 65536);

        uint4 o0, o1;
        {
            __half2 rg0 = __floats2half2_rn(r4.x, g4.x);
            __half2 ba0 = __floats2half2_rn(b4.x, a4.x);
            __half2 rg1 = __floats2half2_rn(r4.y, g4.y);
            __half2 ba1 = __floats2half2_rn(b4.y, a4.y);
            o0.x = *(unsigned int*)&rg0; o0.y = *(unsigned int*)&ba0;
            o0.z = *(unsigned int*)&rg1; o0.w = *(unsigned int*)&ba1;
            __half2 rg2 = __floats2half2_rn(r4.z, g4.z);
            __half2 ba2 = __floats2half2_rn(b4.z, a4.z);
            __half2 rg3 = __floats2half2_rn(r4.w, g4.w);
            __half2 ba3 = __floats2half2_rn(b4.w, a4.w);
            o1.x = *(unsigned int*)&rg2; o1.y = *(unsigned int*)&ba2;
            o1.z = *(unsigned int*)&rg3; o1.w = *(unsigned int*)&ba3;
        }
        uint4* dst = (uint4*)(hbuf + g0);
        dst[0] = o0;
        dst[1] = o1;
        return;
    }

    // ---- prep: this block ranks samples [blockIdx*256, +256) ----
    __shared__ float ds[NS];
    // load all 1024 depths (4 per thread)
    #pragma unroll
    for (int k = 0; k < 4; ++k) {
        const int s = tid + 256 * k;
        ds[s] = data[s * NCOL + 4];
    }
    __syncthreads();

    const int s = (int)blockIdx.x * 256 + tid;
    const float* row = data + s * NCOL;
    const float d = ds[s];
    const int x = (int)rintf(row[0] * (float)HH);   // round-half-even == jnp.round
    const int y = (int)rintf(row[1] * (float)WW);
    const int h = (int)rintf(row[2] * (float)HH);
    const int w = (int)rintf(row[3] * (float)WW);
    const int x1 = x - h / 2;
    const int y1 = y - w / 2;

    float best = row[5];
    int bi = 0;
    #pragma unroll 8
    for (int j = 1; j < NIMG; ++j) {
        float v = row[5 + j];
        if (v > best) { best = v; bi = j; }
    }

    int rank = 0;
    for (int j4 = 0; j4 < NS / 4; ++j4) {
        const float4 dj = *(const float4*)&ds[j4 * 4];   // broadcast b128 read
        const int j0 = j4 * 4;
        rank += (int)((dj.x < d) | ((dj.x == d) & (j0     < s)));
        rank += (int)((dj.y < d) | ((dj.y == d) & (j0 + 1 < s)));
        rank += (int)((dj.z < d) | ((dj.z == d) & (j0 + 2 < s)));
        rank += (int)((dj.w < d) | ((dj.w == d) & (j0 + 3 < s)));
    }
    pos[rank] = ((uint32_t)x1 << 17) | ((uint32_t)y1 << 6) | (uint32_t)bi;
}

// ---------------------------------------------------------------------------
// Composite: one block per 32x32 tile, 4 px/thread. Front-to-back with
// transmittance + per-lane predicated loads + wave-level early termination.
// ---------------------------------------------------------------------------
__global__ __launch_bounds__(256) void comp_half_kernel(const uint2* __restrict__ hbuf,
                                                        const uint32_t* __restrict__ pos,
                                                        float* __restrict__ out) {
    __shared__ uint32_t list[NS];
    __shared__ int wcnt[4];

    const int tid  = threadIdx.x;
    const int lane = tid & 63;
    const int wv   = tid >> 6;

    const int tileR = blockIdx.x >> 6;    // 64x64 tiles of 32x32
    const int tileC = blockIdx.x & 63;
    const int r0 = tileR * 32;
    const int c0 = tileC * 32;

    // ---- binning: sprites whose bbox intersects this tile (depth order) ----
    int run = 0;
    for (int base = 0; base < NS; base += 256) {
        const uint32_t p = pos[base + tid];
        const int x1 = (int)(p >> 17);
        const int y1 = (int)((p >> 6) & 0x7FF);
        const bool hit = (x1 >= r0 - (ESZ - 1)) && (x1 <= r0 + 31) &&
                         (y1 >= c0 - (ESZ - 1)) && (y1 <= c0 + 31);
        const uint64_t m = __ballot(hit);
        if (lane == 0) wcnt[wv] = __popcll(m);
        __syncthreads();
        int off = run;
        for (int w2 = 0; w2 < wv; ++w2) off += wcnt[w2];
        if (hit) {
            const int slot = __popcll(m & ((1ull << lane) - 1ull));
            list[off + slot] = p;
        }
        run += wcnt[0] + wcnt[1] + wcnt[2] + wcnt[3];
        __syncthreads();
    }
    const int n = run;

    // ---- per-thread: 4 pixels (16x16 quadrants of the 32x32 tile) ----
    const int px0 = c0 + (tid & 15);
    const int py0 = r0 + (tid >> 4);

    float cr[4], cg[4], cb[4], T[4];
    #pragma unroll
    for (int q = 0; q < 4; ++q) { cr[q] = 0.0f; cg[q] = 0.0f; cb[q] = 0.0f; T[q] = 1.0f; }

    // front-to-back: list is sorted back-to-front, so walk it in reverse
    for (int s = n - 1; s >= 0; --s) {
        const uint32_t p = list[s];                 // uniform -> LDS broadcast
        const int x1 = (int)(p >> 17);
        const int y1 = (int)((p >> 6) & 0x7FF);
        const size_t ib = ((size_t)(p & 0x3F)) << 16;
        const int ry = py0 - x1;
        const int rx = px0 - y1;
        #pragma unroll
        for (int q = 0; q < 4; ++q) {
            if (T[q] > EPS_T) {
                const int sy = ry + ((q >> 1) << 4);
                const int sx = rx + ((q & 1) << 4);
                if ((unsigned)sy < ESZ && (unsigned)sx < ESZ) {
                    const uint2 v = hbuf[ib + (size_t)((sy << 8) + sx)];
                    const __half2 rg = *(const __half2*)&v.x;
                    const __half2 ba = *(const __half2*)&v.y;
                    const float sr = __low2float(rg);
                    const float sg = __high2float(rg);
                    const float sb = __low2float(ba);
                    const float a  = __high2float(ba);
                    const float w  = T[q] * a;
                    cr[q] += w * sr;
                    cg[q] += w * sg;
                    cb[q] += w * sb;
                    T[q] *= (1.0f - a);
                }
            }
        }
        const bool alive = (T[0] > EPS_T) | (T[1] > EPS_T) | (T[2] > EPS_T) | (T[3] > EPS_T);
        if (!__any(alive)) break;
    }

    #pragma unroll
    for (int q = 0; q < 4; ++q) {
        const int py = py0 + ((q >> 1) << 4);
        const int px = px0 + ((q & 1) << 4);
        const size_t o = (size_t)py * WW + px;
        out[o]                        = cr[q] + T[q];   // white canvas shows through
        out[(size_t)HH * WW     + o]  = cg[q] + T[q];
        out[(size_t)2 * HH * WW + o]  = cb[q] + T[q];
        out[(size_t)3 * HH * WW + o]  = 1.0f;
    }
}

// ---------------------------------------------------------------------------
// Fallback (fp32 planar, back-to-front "over") — only if ws too small.
// ---------------------------------------------------------------------------
__global__ __launch_bounds__(1024) void prep_kernel(const float* __restrict__ data,
                                                    uint32_t* __restrict__ pos) {
    __shared__ float ds[NS];
    const int t = threadIdx.x;
    const float* row = data + t * NCOL;
    const float d = row[4];
    const int x = (int)rintf(row[0] * (float)HH);
    const int y = (int)rintf(row[1] * (float)WW);
    const int h = (int)rintf(row[2] * (float)HH);
    const int w = (int)rintf(row[3] * (float)WW);
    const int x1 = x - h / 2;
    const int y1 = y - w / 2;
    float best = row[5];
    int bi = 0;
    for (int j = 1; j < NIMG; ++j) {
        float v = row[5 + j];
        if (v > best) { best = v; bi = j; }
    }
    ds[t] = d;
    __syncthreads();
    int rank = 0;
    for (int j = 0; j < NS; ++j) {
        float dj = ds[j];
        rank += (int)((dj < d) | ((dj == d) & (j < t)));
    }
    pos[rank] = ((uint32_t)x1 << 17) | ((uint32_t)y1 << 6) | (uint32_t)bi;
}

__global__ __launch_bounds__(256) void comp_kernel(const float* __restrict__ images,
                                                   const uint32_t* __restrict__ pos,
                                                   float* __restrict__ out) {
    __shared__ uint32_t list[NS];
    __shared__ int wcnt[4];
    const int tid  = threadIdx.x;
    const int lane = tid & 63;
    const int wv   = tid >> 6;
    const int tileR = blockIdx.x >> 7;
    const int tileC = blockIdx.x & 127;
    const int r0 = tileR * 16;
    const int c0 = tileC * 16;
    int run = 0;
    for (int base = 0; base < NS; base += 256) {
        const uint32_t p = pos[base + tid];
        const int x1 = (int)(p >> 17);
        const int y1 = (int)((p >> 6) & 0x7FF);
        const bool hit = (x1 >= r0 - (ESZ - 1)) && (x1 <= r0 + 15) &&
                         (y1 >= c0 - (ESZ - 1)) && (y1 <= c0 + 15);
        const uint64_t m = __ballot(hit);
        if (lane == 0) wcnt[wv] = __popcll(m);
        __syncthreads();
        int off = run;
        for (int w2 = 0; w2 < wv; ++w2) off += wcnt[w2];
        if (hit) {
            const int slot = __popcll(m & ((1ull << lane) - 1ull));
            list[off + slot] = p;
        }
        run += wcnt[0] + wcnt[1] + wcnt[2] + wcnt[3];
        __syncthreads();
    }
    const int n = run;
    const int px = c0 + (tid & 15);
    const int py = r0 + (tid >> 4);
    float r = 1.0f, g = 1.0f, b = 1.0f;
    for (int s = 0; s < n; ++s) {
        const uint32_t p = list[s];
        const int x1 = (int)(p >> 17);
        const int y1 = (int)((p >> 6) & 0x7FF);
        const int ii = (int)(p & 0x3F);
        const int sy = py - x1;
        const int sx = px - y1;
        if ((unsigned)sy < ESZ && (unsigned)sx < ESZ) {
            const float* sp = images + (size_t)ii * (4 * ESZ * ESZ) + sy * ESZ + sx;
            const float sr = sp[0];
            const float sg = sp[ESZ * ESZ];
            const float sb = sp[2 * ESZ * ESZ];
            const float a  = sp[3 * ESZ * ESZ];
            const float ia = 1.0f - a;
            r = r * ia + sr * a;
            g = g * ia + sg * a;
            b = b * ia + sb * a;
        }
    }
    const size_t o = (size_t)py * WW + px;
    out[o]                        = r;
    out[(size_t)HH * WW     + o]  = g;
    out[(size_t)2 * HH * WW + o]  = b;
    out[(size_t)3 * HH * WW + o]  = 1.0f;
}

extern "C" void kernel_launch(void* const* d_in, const int* in_sizes, int n_in,
                              void* d_out, int out_size, void* d_ws, size_t ws_size,
                              hipStream_t stream) {
    const float* data   = (const float*)d_in[0];
    const float* images = (const float*)d_in[1];
    float* out          = (float*)d_out;

    uint32_t* pos = (uint32_t*)d_ws;                           // 4 KB
    const size_t hbuf_off = 4096;
    const size_t hbuf_bytes = (size_t)NIMG * 65536 * 8;        // 33.5 MB fp16 RGBA

    if (ws_size >= hbuf_off + hbuf_bytes) {
        uint2* hbuf = (uint2*)((char*)d_ws + hbuf_off);
        prep_interleave_kernel<<<NBLK_PREP + NBLK_IL, 256, 0, stream>>>(data, images, hbuf, pos);
        comp_half_kernel<<<(HH / 32) * (WW / 32), 256, 0, stream>>>(hbuf, pos, out);
    } else {
        prep_kernel<<<1, NS, 0, stream>>>(data, pos);
        comp_kernel<<<(HH / 16) * (WW / 16), 256, 0, stream>>>(images, pos, out);
    }
}